// Round 8
// baseline (3663.412 us; speedup 1.0000x reference)
//
#include <hip/hip_runtime.h>

typedef unsigned short u16;

static __device__ __forceinline__ float b2f(u16 u) {
  unsigned int x = ((unsigned int)u) << 16;
  return __builtin_bit_cast(float, x);
}
static __device__ __forceinline__ u16 f2b(float f) {
  unsigned int x = __builtin_bit_cast(unsigned int, f);
  unsigned int r = (x + 0x7fffu + ((x >> 16) & 1u)) >> 16;
  return (u16)r;
}
static __device__ __forceinline__ float fin(float x) { return (x != x) ? 0.f : x; }

#define SCALE 0.04419417382415922f  // 1/sqrt(512)

// Q stash layout: bf16 Q row t (512 u16 = 1024 B) lives at byte offset t*4096 of
// d_out, i.e. inside fp32-row t's passthrough region (bytes t*4096..+2047).
// read_kernel only writes bytes t*4096+2048..+4095 (the fp32 read-half) -> no
// overlap; copy_in (launched LAST) overwrites the stash with the exact fp32 X.
// Q row stride in u16 units: 2048.

// ---------------- K1: QKV projection (+bias), fp32 VALU tiled GEMM ----------------
// C[t,k] = sum_c X[t,c]*W[k,c] + bias[k]; 64x64 tile, 256 threads, 4x4/thread.
// z=0: Q (bf16) -> out stash (stride 2048); z=1: K -> ws; z=2: V -> ws.
__global__ __launch_bounds__(256) void qkv_kernel(
    const float* __restrict__ X,
    const float* __restrict__ Wq, const float* __restrict__ bq,
    const float* __restrict__ Wk, const float* __restrict__ bk,
    const float* __restrict__ Wv, const float* __restrict__ bv,
    u16* out_u16, u16* __restrict__ Kw, u16* __restrict__ Vw) {
  __shared__ float Xs[64][17];
  __shared__ float Ws[64][17];
  const int z = blockIdx.z;
  const float* W = (z == 0) ? Wq : ((z == 1) ? Wk : Wv);
  const float* bias = (z == 0) ? bq : ((z == 1) ? bk : bv);
  u16* O;
  int ldo;
  if (z == 0) { O = out_u16; ldo = 2048; }   // Q stash
  else if (z == 1) { O = Kw; ldo = 512; }
  else { O = Vw; ldo = 512; }

  const int row0 = blockIdx.x * 64;
  const int col0 = blockIdx.y * 64;
  const int tid = threadIdx.x;
  const int tm = tid >> 4, tn = tid & 15;

  float acc[4][4];
  #pragma unroll
  for (int m = 0; m < 4; ++m)
    #pragma unroll
    for (int n = 0; n < 4; ++n) acc[m][n] = 0.f;

  const int r = tid >> 2;          // 0..63
  const int kc = (tid & 3) * 4;    // 0,4,8,12

  for (int k0 = 0; k0 < 512; k0 += 16) {
    __syncthreads();
    {
      float4 xv = *(const float4*)&X[(size_t)(row0 + r) * 512 + k0 + kc];
      float4 wv = *(const float4*)&W[(size_t)(col0 + r) * 512 + k0 + kc];
      Xs[r][kc] = xv.x; Xs[r][kc + 1] = xv.y; Xs[r][kc + 2] = xv.z; Xs[r][kc + 3] = xv.w;
      Ws[r][kc] = wv.x; Ws[r][kc + 1] = wv.y; Ws[r][kc + 2] = wv.z; Ws[r][kc + 3] = wv.w;
    }
    __syncthreads();
    #pragma unroll
    for (int kk = 0; kk < 16; ++kk) {
      float xa[4], wb[4];
      #pragma unroll
      for (int m = 0; m < 4; ++m) xa[m] = Xs[tm * 4 + m][kk];
      #pragma unroll
      for (int n = 0; n < 4; ++n) wb[n] = Ws[tn * 4 + n][kk];
      #pragma unroll
      for (int m = 0; m < 4; ++m)
        #pragma unroll
        for (int n = 0; n < 4; ++n) acc[m][n] += xa[m] * wb[n];
    }
  }

  #pragma unroll
  for (int m = 0; m < 4; ++m)
    #pragma unroll
    for (int n = 0; n < 4; ++n) {
      int row = row0 + tm * 4 + m;
      int col = col0 + tn * 4 + n;
      O[(size_t)row * ldo + col] = f2b(fin(acc[m][n] + bias[col]));
    }
}

// ---------------- K2: denom + fold into V ----------------
// Block (ic,b): i = 4*ic..4*ic+3. denom[i] = sum_{j>=i} exp(S[j,i]*SCALE);
// then V[i][:] *= 1/denom[i] in place. Q read from out stash (stride 2048).
__global__ __launch_bounds__(256) void denomscale_kernel(
    const u16* out_q, const u16* __restrict__ Kw, u16* __restrict__ Vw) {
  __shared__ float red[4][4];
  const int b = blockIdx.y;
  const int i0 = blockIdx.x * 4;
  const int tid = threadIdx.x, lane = tid & 63, w = tid >> 6;

  float kr[4][8];
  #pragma unroll
  for (int m = 0; m < 4; ++m) {
    uint4 kv = *(const uint4*)&Kw[(size_t)(b * 2048 + i0 + m) * 512 + lane * 8];
    const u16* h = (const u16*)&kv;
    #pragma unroll
    for (int t = 0; t < 8; ++t) kr[m][t] = b2f(h[t]);
  }

  float part[4] = {0.f, 0.f, 0.f, 0.f};
  for (int j = i0 + w; j < 2048; j += 4) {
    uint4 qv = *(const uint4*)&out_q[(size_t)(b * 2048 + j) * 2048 + lane * 8];
    const u16* qh = (const u16*)&qv;
    float q[8];
    #pragma unroll
    for (int t = 0; t < 8; ++t) q[t] = b2f(qh[t]);
    #pragma unroll
    for (int m = 0; m < 4; ++m) {
      float s = 0.f;
      #pragma unroll
      for (int t = 0; t < 8; ++t) s += q[t] * kr[m][t];
      s += __shfl_xor(s, 1);  s += __shfl_xor(s, 2);  s += __shfl_xor(s, 4);
      s += __shfl_xor(s, 8);  s += __shfl_xor(s, 16); s += __shfl_xor(s, 32);
      if (j >= i0 + m)
        part[m] += __expf(fminf(fmaxf(s * SCALE, -80.f), 80.f));
    }
  }
  if (lane == 0) {
    #pragma unroll
    for (int m = 0; m < 4; ++m) red[w][m] = part[m];
  }
  __syncthreads();

  const float d = red[0][w] + red[1][w] + red[2][w] + red[3][w];
  const float rd = 1.0f / fmaxf(fin(d), 1e-20f);
  u16* p = &Vw[(size_t)(b * 2048 + i0 + w) * 512 + lane * 8];
  uint4 vv = *(const uint4*)p;
  u16* h = (u16*)&vv;
  #pragma unroll
  for (int q = 0; q < 8; ++q) h[q] = f2b(fin(b2f(h[q]) * rd));
  *(uint4*)p = vv;
}

// ---------------- K3: read row: block (j, b), fp32 output ----------------
// Phase A: srow[i] = exp(S[j,i]*SCALE), i<=j. Phase B: outf[j,512+v] = sum srow*V'.
__global__ __launch_bounds__(256) void read_kernel(
    const u16* out_q, const u16* __restrict__ Kw, const u16* __restrict__ Vw,
    float* outf) {
  __shared__ float srow[2048];
  const int j = blockIdx.x, b = blockIdx.y;
  const int tid = threadIdx.x, lane = tid & 63, w = tid >> 6;

  uint4 qv = *(const uint4*)&out_q[(size_t)(b * 2048 + j) * 2048 + lane * 8];
  const u16* qh = (const u16*)&qv;
  float q[8];
  #pragma unroll
  for (int t = 0; t < 8; ++t) q[t] = b2f(qh[t]);

  for (int i = w; i <= j; i += 4) {
    uint4 kv = *(const uint4*)&Kw[(size_t)(b * 2048 + i) * 512 + lane * 8];
    const u16* kh = (const u16*)&kv;
    float s = 0.f;
    #pragma unroll
    for (int t = 0; t < 8; ++t) s += q[t] * b2f(kh[t]);
    s += __shfl_xor(s, 1);  s += __shfl_xor(s, 2);  s += __shfl_xor(s, 4);
    s += __shfl_xor(s, 8);  s += __shfl_xor(s, 16); s += __shfl_xor(s, 32);
    if (lane == 0)
      srow[i] = __expf(fminf(fmaxf(s * SCALE, -80.f), 80.f));
  }
  __syncthreads();

  const int v0 = tid * 2;
  float a0 = 0.f, a1 = 0.f;
  for (int i = 0; i <= j; ++i) {
    float p = srow[i];
    unsigned vv = *(const unsigned*)&Vw[(size_t)(b * 2048 + i) * 512 + v0];
    a0 += p * b2f((u16)(vv & 0xffffu));
    a1 += p * b2f((u16)(vv >> 16));
  }
  float2 res = make_float2(fin(a0), fin(a1));
  *(float2*)&outf[((size_t)b * 2048 + j) * 1024 + 512 + v0] = res;
}

// ---------------- K4: passthrough fp32 X -> fp32 out[:,0:512] (LAST) ----------------
__global__ __launch_bounds__(256) void copy_in_kernel(
    const float* __restrict__ X, float* __restrict__ outf) {
  size_t idx = (size_t)blockIdx.x * 256 + threadIdx.x;  // 2,097,152 float4 chunks
  size_t row = idx >> 7;
  int c = (int)(idx & 127) * 4;
  *(float4*)&outf[row * 1024 + c] = *(const float4*)&X[row * 512 + c];
}

extern "C" void kernel_launch(void* const* d_in, const int* in_sizes, int n_in,
                              void* d_out, int out_size, void* d_ws, size_t ws_size,
                              hipStream_t stream) {
  const float* X  = (const float*)d_in[0];
  const float* Wq = (const float*)d_in[1];
  const float* bq = (const float*)d_in[2];
  const float* Wk = (const float*)d_in[3];
  const float* bk = (const float*)d_in[4];
  const float* Wv = (const float*)d_in[5];
  const float* bv = (const float*)d_in[6];
  float* outf = (float*)d_out;
  u16* out_u16 = (u16*)d_out;

  // ws: K @0 (16.78MB), V @16.78MB -- exactly 33,554,432 B.
  char* ws = (char*)d_ws;
  const size_t SZ = (size_t)16384 * 512 * sizeof(u16);
  u16* Kw = (u16*)(ws);
  u16* Vw = (u16*)(ws + SZ);

  qkv_kernel<<<dim3(256, 8, 3), 256, 0, stream>>>(X, Wq, bq, Wk, bk, Wv, bv, out_u16, Kw, Vw);
  denomscale_kernel<<<dim3(512, 8), 256, 0, stream>>>(out_u16, Kw, Vw);
  read_kernel<<<dim3(2048, 8), 256, 0, stream>>>(out_u16, Kw, Vw, outf);
  copy_in_kernel<<<8192, 256, 0, stream>>>(X, outf);
}